// Round 1
// baseline (309.456 us; speedup 1.0000x reference)
//
#include <hip/hip_runtime.h>
#include <math.h>

#define NN 50000
#define NE 800000
#define DD 128
#define NBKT 196            // coarse buckets: row >> 8
#define BCAP 5120           // per-bucket capacity (mean 4082 -> 16-sigma margin)
#define CHUNK 2048          // edges per bin_kernel block
#define NCHUNK ((NE + CHUNK - 1) / CHUNK)   // 391
#define SPMM_NBLK (NN / 16) // 3125
// quarter-split SpMM: 4 column-quarters x 3125 row-blocks, XCD-paired.
// grid = 8 * ceil(3125/2); q = (b&7)>>1 pins quarter q to XCDs {2q,2q+1}
#define NQBLK (8 * ((SPMM_NBLK + 1) / 2))   // 12504

// weights
#define W1 1.0f
#define W2 1.0f
#define W3 7.81f
#define W4 45.28f

// ---------------- bf16 helpers (x stored as bf16 pairs packed in uint) ----------------
static __device__ __forceinline__ float blo(unsigned int p) { return __uint_as_float(p << 16); }
static __device__ __forceinline__ float bhi(unsigned int p) { return __uint_as_float(p & 0xffff0000u); }
static __device__ __forceinline__ unsigned int pack2bf(float a, float b) {
    unsigned int ua = __float_as_uint(a);
    unsigned int ub = __float_as_uint(b);
    ua = ua + 0x7FFFu + ((ua >> 16) & 1u);
    ub = ub + 0x7FFFu + ((ub >> 16) & 1u);
    return (ua >> 16) | (ub & 0xffff0000u);
}

// ---------------- pass 1: LDS counting-sort edges into 196 coarse buckets ----------------
static __global__ __launch_bounds__(256) void bin_kernel(
    const int* __restrict__ erow, const int* __restrict__ ecol, const float* __restrict__ eval_,
    int* __restrict__ bucket_cursor, uint2* __restrict__ binned) {
    __shared__ uint2 sorted[CHUNK];
    __shared__ unsigned short sbin[CHUNK];
    __shared__ int hist[NBKT];
    __shared__ int bstart[NBKT];
    __shared__ int bcur[NBKT];
    __shared__ int gbase[NBKT];
    __shared__ int tmp[256];

    int t = threadIdx.x;
    int cbase = blockIdx.x * CHUNK;
    int cn = NE - cbase; if (cn > CHUNK) cn = CHUNK;

    for (int i = t; i < NBKT; i += 256) hist[i] = 0;
    __syncthreads();

    unsigned int rc[8]; unsigned int vv[8]; int bb[8];
    int nloc = 0;
    for (int i = t; i < cn; i += 256) {
        int g = cbase + i;
        int r = erow[g];
        int c = ecol[g];
        float v = eval_[g];
        rc[nloc] = (unsigned)r | ((unsigned)c << 16);
        vv[nloc] = __float_as_uint(v);
        int b = r >> 8;
        bb[nloc] = b;
        atomicAdd(&hist[b], 1);
        ++nloc;
    }
    __syncthreads();

    int hv = (t < NBKT) ? hist[t] : 0;
    tmp[t] = hv;
    __syncthreads();
    for (int off = 1; off < 256; off <<= 1) {
        int u = (t >= off) ? tmp[t - off] : 0;
        __syncthreads();
        tmp[t] += u;
        __syncthreads();
    }
    if (t < NBKT) {
        int ex = tmp[t] - hv;
        bstart[t] = ex;
        bcur[t] = ex;
        gbase[t] = atomicAdd(&bucket_cursor[t], hv);
    }
    __syncthreads();

    for (int k = 0; k < nloc; ++k) {
        int pos = atomicAdd(&bcur[bb[k]], 1);
        sorted[pos] = make_uint2(rc[k], vv[k]);
        sbin[pos] = (unsigned short)bb[k];
    }
    __syncthreads();

    for (int i = t; i < cn; i += 256) {
        int b = sbin[i];
        binned[(size_t)b * BCAP + gbase[b] + (i - bstart[b])] = sorted[i];
    }
}

// ---------------- pass 2: per-bucket sort by row -> CSR + row_start + deg + x0 ----------
// x0 written in QUARTER layout: uint index (q*NN + node)*16 + sub covers cols 32q+2sub(,+1)
static __global__ __launch_bounds__(256) void sort_kernel(
    const uint2* __restrict__ binned, const int* __restrict__ bucket_cursor,
    uint2* __restrict__ csr, int* __restrict__ row_start, float* __restrict__ deg,
    const float* __restrict__ R, uint4* __restrict__ x0) {
    __shared__ uint2 buf[BCAP];
    __shared__ int hist[256];
    __shared__ int rcur[256];
    __shared__ float fdeg[256];
    __shared__ int pscan[256];
    int b = blockIdx.x;
    int t = threadIdx.x;
    int lo = b << 8;

    int pv = (t < NBKT) ? bucket_cursor[t] : 0;
    pscan[t] = pv;
    hist[t] = 0;
    fdeg[t] = 0.0f;
    __syncthreads();
    for (int off = 1; off < 256; off <<= 1) {
        int u = (t >= off) ? pscan[t - off] : 0;
        __syncthreads();
        pscan[t] += u;
        __syncthreads();
    }
    int gb = (b == 0) ? 0 : pscan[b - 1];
    int cnt = pscan[b] - gb;

    for (int i = t; i < cnt; i += 256) {
        uint2 e = binned[(size_t)b * BCAP + i];
        buf[i] = e;
        int rr = (int)(e.x & 0xFFFFu) - lo;
        atomicAdd(&hist[rr], 1);
        atomicAdd(&fdeg[rr], __uint_as_float(e.y));
    }
    __syncthreads();
    int hv = hist[t];
    rcur[t] = hv;
    __syncthreads();
    for (int off = 1; off < 256; off <<= 1) {
        int u = (t >= off) ? rcur[t - off] : 0;
        __syncthreads();
        rcur[t] += u;
        __syncthreads();
    }
    int excl = rcur[t] - hv;
    int r = lo + t;
    if (r < NN) {
        row_start[r] = gb + excl;
        float d = fdeg[t];
        deg[r] = (d == 0.0f) ? 1.0f : d;
    }
    if (b == NBKT - 1 && t == 255) row_start[NN] = gb + cnt;
    rcur[t] = excl;
    __syncthreads();
    for (int i = t; i < cnt; i += 256) {
        uint2 e = buf[i];
        int rr = (int)(e.x & 0xFFFFu) - lo;
        int pos = atomicAdd(&rcur[rr], 1);
        csr[(size_t)gb + pos] = make_uint2(e.x >> 16, e.y);
    }

    // x0 init for this block's rows (quarter layout)
    int nrows = NN - lo; if (nrows > 256) nrows = 256;
    const float4* __restrict__ R4 = (const float4*)R;
    for (int idx = t; idx < nrows * 16; idx += 256) {
        int rr = idx >> 4;
        int s = idx & 15;          // uint4 #s covers cols 8s..8s+7 -> uints j=4s..4s+3
        float d = fdeg[rr];
        d = (d == 0.0f) ? 1.0f : d;
        float sc = rsqrtf(d);
        int node = lo + rr;
        size_t g = (size_t)node * 16 + s;
        float4 f0 = R4[g * 2];
        float4 f1 = R4[g * 2 + 1];
        // quarter q = (4s)>>4 = s>>2 ; uint-in-quarter base = (s&3)*4 ; 16B aligned -> uint4 store
        size_t gq = ((size_t)(s >> 2) * NN + (size_t)node) * 4 + (size_t)(s & 3);
        x0[gq] = make_uint4(pack2bf(f0.x * sc, f0.y * sc), pack2bf(f0.z * sc, f0.w * sc),
                            pack2bf(f1.x * sc, f1.y * sc), pack2bf(f1.z * sc, f1.w * sc));
    }
}

// ---------------- quarter-split SpMM hop (hops 1-3) ----------------
// Each block handles 16 rows of ONE column-quarter (32 cols). quarter = (b&7)>>1
// pins each quarter to one XCD pair so the 3.2 MB gather set is L2-resident.
// Output: hops 1-2 -> quarter layout xout; hop 3 -> FULL layout xfull (uint 16q+sub of row).
// Per-quarter sum-of-squares -> ssbuf[q*NN+row]; norms finalized in the combine kernel.
static __global__ __launch_bounds__(256) void spmm_q_kernel(
    const int* __restrict__ row_start, const uint2* __restrict__ csr,
    const unsigned int* __restrict__ xq, const float* __restrict__ deg,
    unsigned int* __restrict__ xout, unsigned int* __restrict__ xfull,
    float* __restrict__ ssbuf) {
    int b = blockIdx.x;
    int q = (b & 7) >> 1;
    int rblk = ((b >> 3) << 1) + (b & 1);
    if (rblk >= SPMM_NBLK) return;
    int wave = threadIdx.x >> 6;
    int lane = threadIdx.x & 63;
    int quarter = lane >> 4;   // which of the wave's 4 rows
    int sub = lane & 15;       // uint #sub of this quarter (cols 32q+2sub, +1)
    int row = rblk * 16 + wave * 4 + quarter;
    int s = row_start[row];
    int e = row_start[row + 1];
    size_t qbase = (size_t)q * NN * 16;   // uints

    float a0 = 0.f, a1 = 0.f;
    for (int base = s; base < e; base += 16) {
        int j = base + sub;
        unsigned long long pkt = 0ull;
        if (j < e) pkt = __builtin_nontemporal_load((const unsigned long long*)csr + j);
        int cl = (int)(unsigned int)pkt;
        float vl = __uint_as_float((unsigned int)(pkt >> 32));  // 0 for padded slots
        int cnt = e - base; if (cnt > 16) cnt = 16;
        for (int k = 0; k < cnt; k += 4) {
            int l0 = quarter * 16 + k;
            int c0 = __shfl(cl, l0);
            int c1 = __shfl(cl, l0 + 1);
            int c2 = __shfl(cl, l0 + 2);
            int c3 = __shfl(cl, l0 + 3);
            float v0 = __shfl(vl, l0);
            float v1 = __shfl(vl, l0 + 1);
            float v2 = __shfl(vl, l0 + 2);
            float v3 = __shfl(vl, l0 + 3);
            unsigned int u0 = xq[qbase + (size_t)c0 * 16 + sub];
            unsigned int u1 = xq[qbase + (size_t)c1 * 16 + sub];
            unsigned int u2 = xq[qbase + (size_t)c2 * 16 + sub];
            unsigned int u3 = xq[qbase + (size_t)c3 * 16 + sub];
            a0 += v0 * blo(u0); a1 += v0 * bhi(u0);
            a0 += v1 * blo(u1); a1 += v1 * bhi(u1);
            a0 += v2 * blo(u2); a1 += v2 * bhi(u2);
            a0 += v3 * blo(u3); a1 += v3 * bhi(u3);
        }
    }

    float id = 1.0f / deg[row];
    a0 *= id; a1 *= id;

    float ss = a0 * a0 + a1 * a1;
#pragma unroll
    for (int m = 1; m <= 8; m <<= 1) ss += __shfl_xor(ss, m);

    unsigned int pk = pack2bf(a0, a1);
    if (xout) {
        __builtin_nontemporal_store(pk, &xout[qbase + (size_t)row * 16 + sub]);
    } else {
        __builtin_nontemporal_store(pk, &xfull[(size_t)row * 64 + (size_t)(q * 16 + sub)]);
    }
    if (sub == 0) ssbuf[q * NN + row] = ss;
}

// ---------------- hop 4: full-width SpMM + combine + per-block column stats ----------------
// Gather input xin = x3 in FULL layout (unchanged structure). Epilogue reads x1/x2 in
// quarter layout and finalizes hop 1-3 norms from the ssb partials (fixed summation order).
static __global__ __launch_bounds__(256) void spmm_last_kernel(
    const int* __restrict__ row_start, const uint2* __restrict__ csr,
    const uint4* __restrict__ xin, const float* __restrict__ deg,
    const unsigned int* __restrict__ x1q, const unsigned int* __restrict__ x2q,
    const uint4* __restrict__ x3f,
    const float* __restrict__ ssb1, const float* __restrict__ ssb2, const float* __restrict__ ssb3,
    float* __restrict__ out, float* __restrict__ psum, float* __restrict__ psumsq) {
    __shared__ float shs[256 * 8];
    __shared__ float shq[256 * 8];
    int wave = threadIdx.x >> 6;
    int lane = threadIdx.x & 63;
    int quarter = lane >> 4;
    int sub = lane & 15;
    int row = blockIdx.x * 16 + wave * 4 + quarter;
    int s = row_start[row];
    int e = row_start[row + 1];

    float a0 = 0.f, a1 = 0.f, a2 = 0.f, a3 = 0.f, a4 = 0.f, a5 = 0.f, a6 = 0.f, a7 = 0.f;
    for (int base = s; base < e; base += 16) {
        int j = base + sub;
        unsigned long long pkt = 0ull;
        if (j < e) pkt = __builtin_nontemporal_load((const unsigned long long*)csr + j);
        int cl = (int)(unsigned int)pkt;
        float vl = __uint_as_float((unsigned int)(pkt >> 32));
        int cnt = e - base; if (cnt > 16) cnt = 16;
        for (int k = 0; k < cnt; k += 4) {
            int l0 = quarter * 16 + k;
            int c0 = __shfl(cl, l0);
            int c1 = __shfl(cl, l0 + 1);
            int c2 = __shfl(cl, l0 + 2);
            int c3 = __shfl(cl, l0 + 3);
            float v0 = __shfl(vl, l0);
            float v1 = __shfl(vl, l0 + 1);
            float v2 = __shfl(vl, l0 + 2);
            float v3 = __shfl(vl, l0 + 3);
            uint4 p0 = xin[(size_t)c0 * 16 + sub];
            uint4 p1 = xin[(size_t)c1 * 16 + sub];
            uint4 p2 = xin[(size_t)c2 * 16 + sub];
            uint4 p3 = xin[(size_t)c3 * 16 + sub];
            a0 += v0 * blo(p0.x); a1 += v0 * bhi(p0.x); a2 += v0 * blo(p0.y); a3 += v0 * bhi(p0.y);
            a4 += v0 * blo(p0.z); a5 += v0 * bhi(p0.z); a6 += v0 * blo(p0.w); a7 += v0 * bhi(p0.w);
            a0 += v1 * blo(p1.x); a1 += v1 * bhi(p1.x); a2 += v1 * blo(p1.y); a3 += v1 * bhi(p1.y);
            a4 += v1 * blo(p1.z); a5 += v1 * bhi(p1.z); a6 += v1 * blo(p1.w); a7 += v1 * bhi(p1.w);
            a0 += v2 * blo(p2.x); a1 += v2 * bhi(p2.x); a2 += v2 * blo(p2.y); a3 += v2 * bhi(p2.y);
            a4 += v2 * blo(p2.z); a5 += v2 * bhi(p2.z); a6 += v2 * blo(p2.w); a7 += v2 * bhi(p2.w);
            a0 += v3 * blo(p3.x); a1 += v3 * bhi(p3.x); a2 += v3 * blo(p3.y); a3 += v3 * bhi(p3.y);
            a4 += v3 * blo(p3.z); a5 += v3 * bhi(p3.z); a6 += v3 * blo(p3.w); a7 += v3 * bhi(p3.w);
        }
    }

    float id = 1.0f / deg[row];
    a0 *= id; a1 *= id; a2 *= id; a3 *= id; a4 *= id; a5 *= id; a6 *= id; a7 *= id;

    float ss = a0 * a0 + a1 * a1 + a2 * a2 + a3 * a3 + a4 * a4 + a5 * a5 + a6 * a6 + a7 * a7;
#pragma unroll
    for (int m = 1; m <= 8; m <<= 1) ss += __shfl_xor(ss, m);
    float nrm = fmaxf(sqrtf(ss), 1e-12f);
    float w4 = W4 / nrm;

    // finalize hop 1-3 norms from per-quarter partials (deterministic order)
    float ss1 = ssb1[row] + ssb1[NN + row] + ssb1[2 * NN + row] + ssb1[3 * NN + row];
    float ss2 = ssb2[row] + ssb2[NN + row] + ssb2[2 * NN + row] + ssb2[3 * NN + row];
    float ss3 = ssb3[row] + ssb3[NN + row] + ssb3[2 * NN + row] + ssb3[3 * NN + row];
    float w1 = W1 / fmaxf(sqrtf(ss1), 1e-12f);
    float w2 = W2 / fmaxf(sqrtf(ss2), 1e-12f);
    float w3 = W3 / fmaxf(sqrtf(ss3), 1e-12f);

    // x1/x2 in quarter layout: lane sub needs uints j=4sub..4sub+3 -> q=sub>>2, 16B aligned
    const uint4* x1q4 = (const uint4*)x1q;
    const uint4* x2q4 = (const uint4*)x2q;
    size_t qi = ((size_t)(sub >> 2) * NN + (size_t)row) * 4 + (size_t)(sub & 3);
    uint4 q1 = x1q4[qi];
    uint4 q2 = x2q4[qi];
    uint4 q3 = x3f[(size_t)row * 16 + sub];

    float v[8];
    v[0] = w1 * blo(q1.x) + w2 * blo(q2.x) + w3 * blo(q3.x) + w4 * a0;
    v[1] = w1 * bhi(q1.x) + w2 * bhi(q2.x) + w3 * bhi(q3.x) + w4 * a1;
    v[2] = w1 * blo(q1.y) + w2 * blo(q2.y) + w3 * blo(q3.y) + w4 * a2;
    v[3] = w1 * bhi(q1.y) + w2 * bhi(q2.y) + w3 * bhi(q3.y) + w4 * a3;
    v[4] = w1 * blo(q1.z) + w2 * blo(q2.z) + w3 * blo(q3.z) + w4 * a4;
    v[5] = w1 * bhi(q1.z) + w2 * bhi(q2.z) + w3 * bhi(q3.z) + w4 * a5;
    v[6] = w1 * blo(q1.w) + w2 * blo(q2.w) + w3 * blo(q3.w) + w4 * a6;
    v[7] = w1 * bhi(q1.w) + w2 * bhi(q2.w) + w3 * bhi(q3.w) + w4 * a7;

    float4* out4 = (float4*)out;
    out4[(size_t)row * 32 + sub * 2]     = make_float4(v[0], v[1], v[2], v[3]);
    out4[(size_t)row * 32 + sub * 2 + 1] = make_float4(v[4], v[5], v[6], v[7]);

    int t = threadIdx.x;
#pragma unroll
    for (int j = 0; j < 8; ++j) {
        shs[t * 8 + j] = v[j];
        shq[t * 8 + j] = v[j] * v[j];
    }
    __syncthreads();
    if (t < DD) {
        int cs = t >> 3, cj = t & 7;
        float sacc = 0.0f, qacc = 0.0f;
        for (int g = 0; g < 16; ++g) {
            int src = (g * 16 + cs) * 8 + cj;
            sacc += shs[src];
            qacc += shq[src];
        }
        psum[(size_t)blockIdx.x * DD + t] = sacc;
        psumsq[(size_t)blockIdx.x * DD + t] = qacc;
    }
}

// ---------------- fold partials per column, compute mean/invstd ----------------
static __global__ __launch_bounds__(256) void fold_kernel(
    const float* __restrict__ psum, const float* __restrict__ psumsq,
    float* __restrict__ mean, float* __restrict__ invstd) {
    __shared__ double ss[256], qq[256];
    int c = blockIdx.x;
    int t = threadIdx.x;
    double s = 0.0, q = 0.0;
    for (int b = t; b < SPMM_NBLK; b += 256) {
        s += (double)psum[(size_t)b * DD + c];
        q += (double)psumsq[(size_t)b * DD + c];
    }
    ss[t] = s; qq[t] = q;
    __syncthreads();
    for (int off = 128; off > 0; off >>= 1) {
        if (t < off) { ss[t] += ss[t + off]; qq[t] += qq[t + off]; }
        __syncthreads();
    }
    if (t == 0) {
        double m = ss[0] / (double)NN;
        double var = (qq[0] - (double)NN * m * m) / (double)(NN - 1);
        if (var < 0.0) var = 0.0;
        double sd = sqrt(var);
        if (sd == 0.0) sd = 1.0;
        mean[c] = (float)m;
        invstd[c] = (float)(1.0 / sd);
    }
}

// ---------------- standardize in place (float4 vectorized) ----------------
static __global__ __launch_bounds__(256) void normalize_kernel(
    float* __restrict__ out, const float* __restrict__ mean, const float* __restrict__ invstd) {
    int i = blockIdx.x * blockDim.x + threadIdx.x;
    int c4 = i & 31;
    float4 m = ((const float4*)mean)[c4];
    float4 is = ((const float4*)invstd)[c4];
    float4* out4 = (float4*)out;
    float4 v = out4[i];
    v.x = (v.x - m.x) * is.x;
    v.y = (v.y - m.y) * is.y;
    v.z = (v.z - m.z) * is.z;
    v.w = (v.w - m.w) * is.w;
    out4[i] = v;
}

extern "C" void kernel_launch(void* const* d_in, const int* in_sizes, int n_in,
                              void* d_out, int out_size, void* d_ws, size_t ws_size,
                              hipStream_t stream) {
    const int* erow = (const int*)d_in[0];
    const int* ecol = (const int*)d_in[1];
    const float* eval_ = (const float*)d_in[2];
    const float* R = (const float*)d_in[3];
    float* out = (float*)d_out;

    char* ws = (char*)d_ws;
    size_t off = 0;
    auto alloc = [&](size_t bytes) -> char* {
        char* p = ws + off;
        off += (bytes + 255) & ~(size_t)255;
        return p;
    };
    float* deg          = (float*)alloc(NN * sizeof(float));
    int* bucket_cursor  = (int*)alloc(NBKT * sizeof(int));
    int* row_start      = (int*)alloc((NN + 1) * sizeof(int));
    uint2* binned       = (uint2*)alloc((size_t)NBKT * BCAP * sizeof(uint2));
    uint2* csr          = (uint2*)alloc((size_t)NE * sizeof(uint2));
    unsigned int* x0    = (unsigned int*)alloc((size_t)NN * 64 * sizeof(unsigned int));  // quarter layout
    unsigned int* x1    = (unsigned int*)alloc((size_t)NN * 64 * sizeof(unsigned int));  // quarter layout
    unsigned int* x2    = (unsigned int*)alloc((size_t)NN * 64 * sizeof(unsigned int));  // quarter layout
    unsigned int* x3    = (unsigned int*)alloc((size_t)NN * 64 * sizeof(unsigned int));  // FULL layout
    float* ssb1         = (float*)alloc((size_t)4 * NN * sizeof(float));
    float* ssb2         = (float*)alloc((size_t)4 * NN * sizeof(float));
    float* ssb3         = (float*)alloc((size_t)4 * NN * sizeof(float));
    float* psum         = (float*)alloc((size_t)SPMM_NBLK * DD * sizeof(float));
    float* psumsq       = (float*)alloc((size_t)SPMM_NBLK * DD * sizeof(float));
    float* meanbuf      = (float*)alloc(DD * sizeof(float));
    float* invstdb      = (float*)alloc(DD * sizeof(float));

    hipMemsetAsync(bucket_cursor, 0, NBKT * sizeof(int), stream);

    bin_kernel<<<NCHUNK, 256, 0, stream>>>(erow, ecol, eval_, bucket_cursor, binned);
    sort_kernel<<<NBKT, 256, 0, stream>>>(binned, bucket_cursor, csr, row_start, deg, R,
                                          (uint4*)x0);

    // hops 1-3: XCD-pinned column-quarter passes, gather set L2-resident
    spmm_q_kernel<<<NQBLK, 256, 0, stream>>>(row_start, csr, x0, deg, x1, nullptr, ssb1);
    spmm_q_kernel<<<NQBLK, 256, 0, stream>>>(row_start, csr, x1, deg, x2, nullptr, ssb2);
    spmm_q_kernel<<<NQBLK, 256, 0, stream>>>(row_start, csr, x2, deg, nullptr, x3, ssb3);

    // hop 4 (full width) + combine + column stats
    spmm_last_kernel<<<SPMM_NBLK, 256, 0, stream>>>(row_start, csr, (const uint4*)x3, deg,
                                                    x1, x2, (const uint4*)x3,
                                                    ssb1, ssb2, ssb3, out, psum, psumsq);

    fold_kernel<<<DD, 256, 0, stream>>>(psum, psumsq, meanbuf, invstdb);
    normalize_kernel<<<NN * 32 / 256, 256, 0, stream>>>(out, meanbuf, invstdb);
}

// Round 2
// 268.988 us; speedup vs baseline: 1.1504x; 1.1504x over previous
//
#include <hip/hip_runtime.h>
#include <math.h>

#define NN 50000
#define NE 800000
#define DD 128
#define NBKT 196            // coarse buckets: row >> 8
#define BCAP 5120           // per-bucket capacity (mean 4082 -> 16-sigma margin)
#define CHUNK 2048          // edges per bin_kernel block
#define NCHUNK ((NE + CHUNK - 1) / CHUNK)   // 391
#define SPMM_NBLK (NN / 16) // 3125

// ---------------- bf16 helpers (x stored as bf16 pairs packed in uint) ----------------
static __device__ __forceinline__ float blo(unsigned int p) { return __uint_as_float(p << 16); }
static __device__ __forceinline__ float bhi(unsigned int p) { return __uint_as_float(p & 0xffff0000u); }
static __device__ __forceinline__ unsigned int pack2bf(float a, float b) {
    unsigned int ua = __float_as_uint(a);
    unsigned int ub = __float_as_uint(b);
    ua = ua + 0x7FFFu + ((ua >> 16) & 1u);
    ub = ub + 0x7FFFu + ((ub >> 16) & 1u);
    return (ua >> 16) | (ub & 0xffff0000u);
}

// ---------------- pass 1: LDS counting-sort edges into 196 coarse buckets ----------------
// payload: uint2{ row | col<<16, val_bits }  (row, col < 65536)
static __global__ __launch_bounds__(256) void bin_kernel(
    const int* __restrict__ erow, const int* __restrict__ ecol, const float* __restrict__ eval_,
    int* __restrict__ bucket_cursor, uint2* __restrict__ binned) {
    __shared__ uint2 sorted[CHUNK];
    __shared__ unsigned short sbin[CHUNK];
    __shared__ int hist[NBKT];
    __shared__ int bstart[NBKT];
    __shared__ int bcur[NBKT];
    __shared__ int gbase[NBKT];
    __shared__ int tmp[256];

    int t = threadIdx.x;
    int cbase = blockIdx.x * CHUNK;
    int cn = NE - cbase; if (cn > CHUNK) cn = CHUNK;

    for (int i = t; i < NBKT; i += 256) hist[i] = 0;
    __syncthreads();

    unsigned int rc[8]; unsigned int vv[8]; int bb[8];
    int nloc = 0;
    for (int i = t; i < cn; i += 256) {
        int g = cbase + i;
        int r = erow[g];
        int c = ecol[g];
        float v = eval_[g];
        rc[nloc] = (unsigned)r | ((unsigned)c << 16);
        vv[nloc] = __float_as_uint(v);
        int b = r >> 8;
        bb[nloc] = b;
        atomicAdd(&hist[b], 1);
        ++nloc;
    }
    __syncthreads();

    // exclusive scan of hist -> bstart (256-thread Hillis-Steele)
    int hv = (t < NBKT) ? hist[t] : 0;
    tmp[t] = hv;
    __syncthreads();
    for (int off = 1; off < 256; off <<= 1) {
        int u = (t >= off) ? tmp[t - off] : 0;
        __syncthreads();
        tmp[t] += u;
        __syncthreads();
    }
    if (t < NBKT) {
        int ex = tmp[t] - hv;
        bstart[t] = ex;
        bcur[t] = ex;
        gbase[t] = atomicAdd(&bucket_cursor[t], hv);  // reserve contiguous run in bucket region
    }
    __syncthreads();

    // scatter into LDS (sorted by bucket)
    for (int k = 0; k < nloc; ++k) {
        int pos = atomicAdd(&bcur[bb[k]], 1);
        sorted[pos] = make_uint2(rc[k], vv[k]);
        sbin[pos] = (unsigned short)bb[k];
    }
    __syncthreads();

    // coalesced write-out: consecutive i in same bucket -> consecutive global slots
    for (int i = t; i < cn; i += 256) {
        int b = sbin[i];
        binned[(size_t)b * BCAP + gbase[b] + (i - bstart[b])] = sorted[i];
    }
}

// ---------------- pass 2: per-bucket sort by row -> CSR + row_start + deg + x0 ----------
static __global__ __launch_bounds__(256) void sort_kernel(
    const uint2* __restrict__ binned, const int* __restrict__ bucket_cursor,
    uint2* __restrict__ csr, int* __restrict__ row_start, float* __restrict__ deg,
    const float* __restrict__ R, uint4* __restrict__ x0) {
    __shared__ uint2 buf[BCAP];
    __shared__ int hist[256];
    __shared__ int rcur[256];
    __shared__ float fdeg[256];
    __shared__ int pscan[256];
    int b = blockIdx.x;
    int t = threadIdx.x;
    int lo = b << 8;

    int pv = (t < NBKT) ? bucket_cursor[t] : 0;
    pscan[t] = pv;
    hist[t] = 0;
    fdeg[t] = 0.0f;
    __syncthreads();
    for (int off = 1; off < 256; off <<= 1) {
        int u = (t >= off) ? pscan[t - off] : 0;
        __syncthreads();
        pscan[t] += u;
        __syncthreads();
    }
    int gb = (b == 0) ? 0 : pscan[b - 1];
    int cnt = pscan[b] - gb;

    for (int i = t; i < cnt; i += 256) {
        uint2 e = binned[(size_t)b * BCAP + i];
        buf[i] = e;
        int rr = (int)(e.x & 0xFFFFu) - lo;
        atomicAdd(&hist[rr], 1);
        atomicAdd(&fdeg[rr], __uint_as_float(e.y));
    }
    __syncthreads();
    int hv = hist[t];
    rcur[t] = hv;
    __syncthreads();
    for (int off = 1; off < 256; off <<= 1) {
        int u = (t >= off) ? rcur[t - off] : 0;
        __syncthreads();
        rcur[t] += u;
        __syncthreads();
    }
    int excl = rcur[t] - hv;
    int r = lo + t;
    if (r < NN) {
        row_start[r] = gb + excl;
        float d = fdeg[t];
        deg[r] = (d == 0.0f) ? 1.0f : d;
    }
    if (b == NBKT - 1 && t == 255) row_start[NN] = gb + cnt;
    rcur[t] = excl;
    __syncthreads();
    for (int i = t; i < cnt; i += 256) {
        uint2 e = buf[i];
        int rr = (int)(e.x & 0xFFFFu) - lo;
        int pos = atomicAdd(&rcur[rr], 1);
        csr[(size_t)gb + pos] = make_uint2(e.x >> 16, e.y);
    }

    // x0 init for this block's rows (fdeg already in LDS)
    int nrows = NN - lo; if (nrows > 256) nrows = 256;
    const float4* __restrict__ R4 = (const float4*)R;
    for (int idx = t; idx < nrows * 16; idx += 256) {
        int rr = idx >> 4;
        int sub = idx & 15;
        float d = fdeg[rr];
        d = (d == 0.0f) ? 1.0f : d;
        float sc = rsqrtf(d);
        size_t g = (size_t)(lo + rr) * 16 + sub;
        float4 f0 = R4[g * 2];
        float4 f1 = R4[g * 2 + 1];
        x0[g] = make_uint4(pack2bf(f0.x * sc, f0.y * sc), pack2bf(f0.z * sc, f0.w * sc),
                           pack2bf(f1.x * sc, f1.y * sc), pack2bf(f1.z * sc, f1.w * sc));
    }
}

// ---------------- fused SpMM + inv_deg + row-norm scalar (hops 1-3) ----------------
// 256 threads = 4 waves; each wave handles 4 rows, one per 16-lane quarter.
// Inner loop: CSR window prefetch + branchless fully-unrolled 16-edge window.
// Padded slots carry v=0 (and col=0) -> exact-zero contributions, numerics unchanged.
static __global__ __launch_bounds__(256) void spmm_fused_kernel(
    const int* __restrict__ row_start, const uint2* __restrict__ csr,
    const uint4* __restrict__ x4, const float* __restrict__ deg,
    uint4* __restrict__ x_next4, float* __restrict__ s_out, float weight) {
    int wave = threadIdx.x >> 6;
    int lane = threadIdx.x & 63;
    int quarter = lane >> 4;  // 0..3 : which row of the wave's 4
    int sub = lane & 15;      // col group: cols [8*sub, 8*sub+7]
    int row = blockIdx.x * 16 + wave * 4 + quarter;
    int s = row_start[row];
    int e = row_start[row + 1];

    float a0 = 0.f, a1 = 0.f, a2 = 0.f, a3 = 0.f, a4 = 0.f, a5 = 0.f, a6 = 0.f, a7 = 0.f;

    int j0 = s + sub;
    uint2 cur = (j0 < e) ? csr[j0] : make_uint2(0u, 0u);
    for (int base = s; base < e; base += 16) {
        int cl = (int)cur.x;
        float vl = __uint_as_float(cur.y);
        int jn = base + 16 + sub;
        cur = (jn < e) ? csr[jn] : make_uint2(0u, 0u);  // prefetch next window
#pragma unroll
        for (int k = 0; k < 16; k += 4) {
            int l0 = quarter * 16 + k;
            int c0 = __shfl(cl, l0);
            int c1 = __shfl(cl, l0 + 1);
            int c2 = __shfl(cl, l0 + 2);
            int c3 = __shfl(cl, l0 + 3);
            float v0 = __shfl(vl, l0);
            float v1 = __shfl(vl, l0 + 1);
            float v2 = __shfl(vl, l0 + 2);
            float v3 = __shfl(vl, l0 + 3);  // padded slots: v=0 -> contribute exactly 0
            uint4 p0 = x4[(size_t)c0 * 16 + sub];
            uint4 p1 = x4[(size_t)c1 * 16 + sub];
            uint4 p2 = x4[(size_t)c2 * 16 + sub];
            uint4 p3 = x4[(size_t)c3 * 16 + sub];
            a0 += v0 * blo(p0.x); a1 += v0 * bhi(p0.x); a2 += v0 * blo(p0.y); a3 += v0 * bhi(p0.y);
            a4 += v0 * blo(p0.z); a5 += v0 * bhi(p0.z); a6 += v0 * blo(p0.w); a7 += v0 * bhi(p0.w);
            a0 += v1 * blo(p1.x); a1 += v1 * bhi(p1.x); a2 += v1 * blo(p1.y); a3 += v1 * bhi(p1.y);
            a4 += v1 * blo(p1.z); a5 += v1 * bhi(p1.z); a6 += v1 * blo(p1.w); a7 += v1 * bhi(p1.w);
            a0 += v2 * blo(p2.x); a1 += v2 * bhi(p2.x); a2 += v2 * blo(p2.y); a3 += v2 * bhi(p2.y);
            a4 += v2 * blo(p2.z); a5 += v2 * bhi(p2.z); a6 += v2 * blo(p2.w); a7 += v2 * bhi(p2.w);
            a0 += v3 * blo(p3.x); a1 += v3 * bhi(p3.x); a2 += v3 * blo(p3.y); a3 += v3 * bhi(p3.y);
            a4 += v3 * blo(p3.z); a5 += v3 * bhi(p3.z); a6 += v3 * blo(p3.w); a7 += v3 * bhi(p3.w);
        }
    }

    float id = 1.0f / deg[row];
    a0 *= id; a1 *= id; a2 *= id; a3 *= id; a4 *= id; a5 *= id; a6 *= id; a7 *= id;

    float ss = a0 * a0 + a1 * a1 + a2 * a2 + a3 * a3 + a4 * a4 + a5 * a5 + a6 * a6 + a7 * a7;
#pragma unroll
    for (int m = 1; m <= 8; m <<= 1) ss += __shfl_xor(ss, m);
    float nrm = fmaxf(sqrtf(ss), 1e-12f);

    x_next4[(size_t)row * 16 + sub] = make_uint4(pack2bf(a0, a1), pack2bf(a2, a3),
                                                 pack2bf(a4, a5), pack2bf(a6, a7));
    if (sub == 0) s_out[row] = weight / nrm;
}

// ---------------- hop 4: SpMM + combine acc(out) + per-block column stats ----------------
static __global__ __launch_bounds__(256) void spmm_last_kernel(
    const int* __restrict__ row_start, const uint2* __restrict__ csr,
    const uint4* __restrict__ xin, const float* __restrict__ deg,
    const uint4* __restrict__ x1, const uint4* __restrict__ x2, const uint4* __restrict__ x3,
    const float* __restrict__ s1, const float* __restrict__ s2, const float* __restrict__ s3,
    float* __restrict__ out, float* __restrict__ psum, float* __restrict__ psumsq, float weight) {
    __shared__ float shs[256 * 8];
    __shared__ float shq[256 * 8];
    int wave = threadIdx.x >> 6;
    int lane = threadIdx.x & 63;
    int quarter = lane >> 4;
    int sub = lane & 15;
    int row = blockIdx.x * 16 + wave * 4 + quarter;
    int s = row_start[row];
    int e = row_start[row + 1];

    float a0 = 0.f, a1 = 0.f, a2 = 0.f, a3 = 0.f, a4 = 0.f, a5 = 0.f, a6 = 0.f, a7 = 0.f;

    int j0 = s + sub;
    uint2 cur = (j0 < e) ? csr[j0] : make_uint2(0u, 0u);
    for (int base = s; base < e; base += 16) {
        int cl = (int)cur.x;
        float vl = __uint_as_float(cur.y);
        int jn = base + 16 + sub;
        cur = (jn < e) ? csr[jn] : make_uint2(0u, 0u);  // prefetch next window
#pragma unroll
        for (int k = 0; k < 16; k += 4) {
            int l0 = quarter * 16 + k;
            int c0 = __shfl(cl, l0);
            int c1 = __shfl(cl, l0 + 1);
            int c2 = __shfl(cl, l0 + 2);
            int c3 = __shfl(cl, l0 + 3);
            float v0 = __shfl(vl, l0);
            float v1 = __shfl(vl, l0 + 1);
            float v2 = __shfl(vl, l0 + 2);
            float v3 = __shfl(vl, l0 + 3);
            uint4 p0 = xin[(size_t)c0 * 16 + sub];
            uint4 p1 = xin[(size_t)c1 * 16 + sub];
            uint4 p2 = xin[(size_t)c2 * 16 + sub];
            uint4 p3 = xin[(size_t)c3 * 16 + sub];
            a0 += v0 * blo(p0.x); a1 += v0 * bhi(p0.x); a2 += v0 * blo(p0.y); a3 += v0 * bhi(p0.y);
            a4 += v0 * blo(p0.z); a5 += v0 * bhi(p0.z); a6 += v0 * blo(p0.w); a7 += v0 * bhi(p0.w);
            a0 += v1 * blo(p1.x); a1 += v1 * bhi(p1.x); a2 += v1 * blo(p1.y); a3 += v1 * bhi(p1.y);
            a4 += v1 * blo(p1.z); a5 += v1 * bhi(p1.z); a6 += v1 * blo(p1.w); a7 += v1 * bhi(p1.w);
            a0 += v2 * blo(p2.x); a1 += v2 * bhi(p2.x); a2 += v2 * blo(p2.y); a3 += v2 * bhi(p2.y);
            a4 += v2 * blo(p2.z); a5 += v2 * bhi(p2.z); a6 += v2 * blo(p2.w); a7 += v2 * bhi(p2.w);
            a0 += v3 * blo(p3.x); a1 += v3 * bhi(p3.x); a2 += v3 * blo(p3.y); a3 += v3 * bhi(p3.y);
            a4 += v3 * blo(p3.z); a5 += v3 * bhi(p3.z); a6 += v3 * blo(p3.w); a7 += v3 * bhi(p3.w);
        }
    }

    float id = 1.0f / deg[row];
    a0 *= id; a1 *= id; a2 *= id; a3 *= id; a4 *= id; a5 *= id; a6 *= id; a7 *= id;

    float ss = a0 * a0 + a1 * a1 + a2 * a2 + a3 * a3 + a4 * a4 + a5 * a5 + a6 * a6 + a7 * a7;
#pragma unroll
    for (int m = 1; m <= 8; m <<= 1) ss += __shfl_xor(ss, m);
    float nrm = fmaxf(sqrtf(ss), 1e-12f);
    float w4 = weight / nrm;

    // combine: acc = s1*x1 + s2*x2 + s3*x3 + w4 * (f32 hop-4 row)
    size_t xi = (size_t)row * 16 + sub;
    float w1 = s1[row], w2 = s2[row], w3 = s3[row];
    uint4 q1 = x1[xi], q2 = x2[xi], q3 = x3[xi];
    float v[8];
    v[0] = w1 * blo(q1.x) + w2 * blo(q2.x) + w3 * blo(q3.x) + w4 * a0;
    v[1] = w1 * bhi(q1.x) + w2 * bhi(q2.x) + w3 * bhi(q3.x) + w4 * a1;
    v[2] = w1 * blo(q1.y) + w2 * blo(q2.y) + w3 * blo(q3.y) + w4 * a2;
    v[3] = w1 * bhi(q1.y) + w2 * bhi(q2.y) + w3 * bhi(q3.y) + w4 * a3;
    v[4] = w1 * blo(q1.z) + w2 * blo(q2.z) + w3 * blo(q3.z) + w4 * a4;
    v[5] = w1 * bhi(q1.z) + w2 * bhi(q2.z) + w3 * bhi(q3.z) + w4 * a5;
    v[6] = w1 * blo(q1.w) + w2 * blo(q2.w) + w3 * blo(q3.w) + w4 * a6;
    v[7] = w1 * bhi(q1.w) + w2 * bhi(q2.w) + w3 * bhi(q3.w) + w4 * a7;

    float4* out4 = (float4*)out;
    out4[(size_t)row * 32 + sub * 2]     = make_float4(v[0], v[1], v[2], v[3]);
    out4[(size_t)row * 32 + sub * 2 + 1] = make_float4(v[4], v[5], v[6], v[7]);

    int t = threadIdx.x;
#pragma unroll
    for (int j = 0; j < 8; ++j) {
        shs[t * 8 + j] = v[j];
        shq[t * 8 + j] = v[j] * v[j];
    }
    __syncthreads();
    if (t < DD) {  // column c = t; fold the 16 rows of this block
        int cs = t >> 3, cj = t & 7;
        float sacc = 0.0f, qacc = 0.0f;
        for (int g = 0; g < 16; ++g) {
            int src = (g * 16 + cs) * 8 + cj;
            sacc += shs[src];
            qacc += shq[src];
        }
        psum[(size_t)blockIdx.x * DD + t] = sacc;
        psumsq[(size_t)blockIdx.x * DD + t] = qacc;
    }
}

// ---------------- fold partials per column, compute mean/invstd ----------------
static __global__ __launch_bounds__(256) void fold_kernel(
    const float* __restrict__ psum, const float* __restrict__ psumsq,
    float* __restrict__ mean, float* __restrict__ invstd) {
    __shared__ double ss[256], qq[256];
    int c = blockIdx.x;   // 0..127
    int t = threadIdx.x;
    double s = 0.0, q = 0.0;
    for (int b = t; b < SPMM_NBLK; b += 256) {
        s += (double)psum[(size_t)b * DD + c];
        q += (double)psumsq[(size_t)b * DD + c];
    }
    ss[t] = s; qq[t] = q;
    __syncthreads();
    for (int off = 128; off > 0; off >>= 1) {
        if (t < off) { ss[t] += ss[t + off]; qq[t] += qq[t + off]; }
        __syncthreads();
    }
    if (t == 0) {
        double m = ss[0] / (double)NN;
        double var = (qq[0] - (double)NN * m * m) / (double)(NN - 1);
        if (var < 0.0) var = 0.0;
        double sd = sqrt(var);
        if (sd == 0.0) sd = 1.0;
        mean[c] = (float)m;
        invstd[c] = (float)(1.0 / sd);
    }
}

// ---------------- standardize in place (float4 vectorized) ----------------
static __global__ __launch_bounds__(256) void normalize_kernel(
    float* __restrict__ out, const float* __restrict__ mean, const float* __restrict__ invstd) {
    int i = blockIdx.x * blockDim.x + threadIdx.x;  // over NN*32 float4s
    int c4 = i & 31;
    float4 m = ((const float4*)mean)[c4];
    float4 is = ((const float4*)invstd)[c4];
    float4* out4 = (float4*)out;
    float4 v = out4[i];
    v.x = (v.x - m.x) * is.x;
    v.y = (v.y - m.y) * is.y;
    v.z = (v.z - m.z) * is.z;
    v.w = (v.w - m.w) * is.w;
    out4[i] = v;
}

extern "C" void kernel_launch(void* const* d_in, const int* in_sizes, int n_in,
                              void* d_out, int out_size, void* d_ws, size_t ws_size,
                              hipStream_t stream) {
    const int* erow = (const int*)d_in[0];
    const int* ecol = (const int*)d_in[1];
    const float* eval_ = (const float*)d_in[2];
    const float* R = (const float*)d_in[3];
    float* out = (float*)d_out;

    // workspace layout
    char* ws = (char*)d_ws;
    size_t off = 0;
    auto alloc = [&](size_t bytes) -> char* {
        char* p = ws + off;
        off += (bytes + 255) & ~(size_t)255;
        return p;
    };
    float* deg          = (float*)alloc(NN * sizeof(float));
    int* bucket_cursor  = (int*)alloc(NBKT * sizeof(int));
    int* row_start      = (int*)alloc((NN + 1) * sizeof(int));
    uint2* binned       = (uint2*)alloc((size_t)NBKT * BCAP * sizeof(uint2));
    uint2* csr          = (uint2*)alloc((size_t)NE * sizeof(uint2));
    uint4* x0           = (uint4*)alloc((size_t)NN * 16 * sizeof(uint4));  // bf16 packed
    uint4* x1           = (uint4*)alloc((size_t)NN * 16 * sizeof(uint4));
    uint4* x2           = (uint4*)alloc((size_t)NN * 16 * sizeof(uint4));
    uint4* x3           = (uint4*)alloc((size_t)NN * 16 * sizeof(uint4));
    float* s1           = (float*)alloc(NN * sizeof(float));
    float* s2           = (float*)alloc(NN * sizeof(float));
    float* s3           = (float*)alloc(NN * sizeof(float));
    float* psum         = (float*)alloc((size_t)SPMM_NBLK * DD * sizeof(float));
    float* psumsq       = (float*)alloc((size_t)SPMM_NBLK * DD * sizeof(float));
    float* meanbuf      = (float*)alloc(DD * sizeof(float));
    float* invstdb      = (float*)alloc(DD * sizeof(float));

    hipMemsetAsync(bucket_cursor, 0, NBKT * sizeof(int), stream);

    bin_kernel<<<NCHUNK, 256, 0, stream>>>(erow, ecol, eval_, bucket_cursor, binned);
    sort_kernel<<<NBKT, 256, 0, stream>>>(binned, bucket_cursor, csr, row_start, deg, R, x0);

    spmm_fused_kernel<<<SPMM_NBLK, 256, 0, stream>>>(row_start, csr, x0, deg, x1, s1, 1.0f);
    spmm_fused_kernel<<<SPMM_NBLK, 256, 0, stream>>>(row_start, csr, x1, deg, x2, s2, 1.0f);
    spmm_fused_kernel<<<SPMM_NBLK, 256, 0, stream>>>(row_start, csr, x2, deg, x3, s3, 7.81f);
    spmm_last_kernel<<<SPMM_NBLK, 256, 0, stream>>>(row_start, csr, x3, deg, x1, x2, x3,
                                                    s1, s2, s3, out, psum, psumsq, 45.28f);

    fold_kernel<<<DD, 256, 0, stream>>>(psum, psumsq, meanbuf, invstdb);
    normalize_kernel<<<NN * 32 / 256, 256, 0, stream>>>(out, meanbuf, invstdb);
}

// Round 3
// 247.620 us; speedup vs baseline: 1.2497x; 1.0863x over previous
//
#include <hip/hip_runtime.h>
#include <math.h>

#define NN 50000
#define NE 800000
#define DD 128
#define NBKT 256            // buckets; bucket = row / RPB (one block per CU)
#define RPB 196             // rows per bucket (256*196 = 50176 >= NN)
#define BCAP 3840           // per-bucket capacity (mean 3136, sigma 56 -> ~12.5 sigma)
#define CHUNK 2048          // edges per bin_kernel block
#define NCHUNK ((NE + CHUNK - 1) / CHUNK)   // 391
#define SPMM_NBLK (NN / 16) // 3125

// ---------------- bf16 helpers (x stored as bf16 pairs packed in uint) ----------------
static __device__ __forceinline__ float blo(unsigned int p) { return __uint_as_float(p << 16); }
static __device__ __forceinline__ float bhi(unsigned int p) { return __uint_as_float(p & 0xffff0000u); }
static __device__ __forceinline__ unsigned int pack2bf(float a, float b) {
    unsigned int ua = __float_as_uint(a);
    unsigned int ub = __float_as_uint(b);
    ua = ua + 0x7FFFu + ((ua >> 16) & 1u);
    ub = ub + 0x7FFFu + ((ub >> 16) & 1u);
    return (ua >> 16) | (ub & 0xffff0000u);
}

// ---------------- pass 1: LDS counting-sort edges into 256 coarse buckets ----------------
// payload: uint2{ row | col<<16, val_bits }  (row, col < 65536)
static __global__ __launch_bounds__(512) void bin_kernel(
    const int* __restrict__ erow, const int* __restrict__ ecol, const float* __restrict__ eval_,
    int* __restrict__ bucket_cursor, uint2* __restrict__ binned) {
    __shared__ uint2 sorted[CHUNK];
    __shared__ unsigned char sbin[CHUNK];
    __shared__ int hist[NBKT];
    __shared__ int bstart[NBKT];
    __shared__ int bcur[NBKT];
    __shared__ int gbase[NBKT];
    __shared__ int tmp[NBKT];

    int t = threadIdx.x;
    int cbase = blockIdx.x * CHUNK;
    int cn = NE - cbase; if (cn > CHUNK) cn = CHUNK;

    for (int i = t; i < NBKT; i += 512) hist[i] = 0;
    __syncthreads();

    unsigned int rc[4]; unsigned int vv[4]; int bb[4];
    int nloc = 0;
    for (int i = t; i < cn; i += 512) {
        int g = cbase + i;
        int r = erow[g];
        int c = ecol[g];
        float v = eval_[g];
        rc[nloc] = (unsigned)r | ((unsigned)c << 16);
        vv[nloc] = __float_as_uint(v);
        int b = r / RPB;            // compiler emits magic-multiply
        bb[nloc] = b;
        atomicAdd(&hist[b], 1);
        ++nloc;
    }
    __syncthreads();

    // exclusive scan of hist over 256 entries (first 256 threads; all hit barriers)
    int hv = (t < NBKT) ? hist[t] : 0;
    if (t < NBKT) tmp[t] = hv;
    __syncthreads();
    for (int off = 1; off < NBKT; off <<= 1) {
        int u = (t < NBKT && t >= off) ? tmp[t - off] : 0;
        __syncthreads();
        if (t < NBKT) tmp[t] += u;
        __syncthreads();
    }
    if (t < NBKT) {
        int ex = tmp[t] - hv;
        bstart[t] = ex;
        bcur[t] = ex;
        gbase[t] = atomicAdd(&bucket_cursor[t], hv);  // reserve contiguous run in bucket region
    }
    __syncthreads();

    // scatter into LDS (sorted by bucket)
    for (int k = 0; k < nloc; ++k) {
        int pos = atomicAdd(&bcur[bb[k]], 1);
        sorted[pos] = make_uint2(rc[k], vv[k]);
        sbin[pos] = (unsigned char)bb[k];
    }
    __syncthreads();

    // coalesced write-out: consecutive i in same bucket -> consecutive global slots
    for (int i = t; i < cn; i += 512) {
        int b = sbin[i];
        binned[(size_t)b * BCAP + gbase[b] + (i - bstart[b])] = sorted[i];
    }
}

// ---------------- pass 2: per-bucket sort by row -> CSR + row_start + deg ----------
static __global__ __launch_bounds__(512) void sort_kernel(
    const uint2* __restrict__ binned, const int* __restrict__ bucket_cursor,
    uint2* __restrict__ csr, int* __restrict__ row_start, float* __restrict__ deg) {
    __shared__ uint2 buf[BCAP];       // 30 KB
    __shared__ int hist[RPB];
    __shared__ int rcur[RPB];
    __shared__ float fdeg[RPB];
    __shared__ int pscan[NBKT];
    int b = blockIdx.x;
    int t = threadIdx.x;
    int lo = b * RPB;

    // inclusive scan over all bucket counts -> per-block base + count
    int pv = (t < NBKT) ? bucket_cursor[t] : 0;
    if (t < NBKT) pscan[t] = pv;
    if (t < RPB) { hist[t] = 0; fdeg[t] = 0.0f; }
    __syncthreads();
    for (int off = 1; off < NBKT; off <<= 1) {
        int u = (t < NBKT && t >= off) ? pscan[t - off] : 0;
        __syncthreads();
        if (t < NBKT) pscan[t] += u;
        __syncthreads();
    }
    int gb = (b == 0) ? 0 : pscan[b - 1];
    int cnt = pscan[b] - gb;

    for (int i = t; i < cnt; i += 512) {
        uint2 e = binned[(size_t)b * BCAP + i];
        buf[i] = e;
        int rr = (int)(e.x & 0xFFFFu) - lo;
        atomicAdd(&hist[rr], 1);
        atomicAdd(&fdeg[rr], __uint_as_float(e.y));
    }
    __syncthreads();
    // inclusive scan of per-row counts (196 entries)
    int hv = (t < RPB) ? hist[t] : 0;
    if (t < RPB) rcur[t] = hv;
    __syncthreads();
    for (int off = 1; off < RPB; off <<= 1) {
        int u = (t < RPB && t >= off) ? rcur[t - off] : 0;
        __syncthreads();
        if (t < RPB) rcur[t] += u;
        __syncthreads();
    }
    if (t < RPB) {
        int excl = rcur[t] - hv;
        int r = lo + t;
        if (r < NN) {
            row_start[r] = gb + excl;
            float d = fdeg[t];
            deg[r] = (d == 0.0f) ? 1.0f : d;
        }
        rcur[t] = excl;
    }
    if (b == NBKT - 1 && t == 0) row_start[NN] = gb + cnt;
    __syncthreads();
    for (int i = t; i < cnt; i += 512) {
        uint2 e = buf[i];
        int rr = (int)(e.x & 0xFFFFu) - lo;
        int pos = atomicAdd(&rcur[rr], 1);
        csr[(size_t)gb + pos] = make_uint2(e.x >> 16, e.y);
    }
}

// ---------------- x0 = R * deg^(-1/2), bf16-packed (fully parallel) ----------------
static __global__ __launch_bounds__(256) void x0_kernel(
    const float* __restrict__ R, const float* __restrict__ deg, uint4* __restrict__ x0) {
    int idx = blockIdx.x * 256 + threadIdx.x;   // over NN*16 uint4s (= 800000, exact grid)
    int row = idx >> 4;
    float sc = rsqrtf(deg[row]);                // deg already has 0 -> 1 fix
    const float4* __restrict__ R4 = (const float4*)R;
    float4 f0 = R4[(size_t)idx * 2];
    float4 f1 = R4[(size_t)idx * 2 + 1];
    x0[idx] = make_uint4(pack2bf(f0.x * sc, f0.y * sc), pack2bf(f0.z * sc, f0.w * sc),
                         pack2bf(f1.x * sc, f1.y * sc), pack2bf(f1.z * sc, f1.w * sc));
}

// ---------------- fused SpMM + inv_deg + row-norm scalar (hops 1-3) ----------------
// 256 threads = 4 waves; each wave handles 4 rows, one per 16-lane quarter.
static __global__ __launch_bounds__(256) void spmm_fused_kernel(
    const int* __restrict__ row_start, const uint2* __restrict__ csr,
    const uint4* __restrict__ x4, const float* __restrict__ deg,
    uint4* __restrict__ x_next4, float* __restrict__ s_out, float weight) {
    int wave = threadIdx.x >> 6;
    int lane = threadIdx.x & 63;
    int quarter = lane >> 4;  // 0..3 : which row of the wave's 4
    int sub = lane & 15;      // col group: cols [8*sub, 8*sub+7]
    int row = blockIdx.x * 16 + wave * 4 + quarter;
    int s = row_start[row];
    int e = row_start[row + 1];

    float a0 = 0.f, a1 = 0.f, a2 = 0.f, a3 = 0.f, a4 = 0.f, a5 = 0.f, a6 = 0.f, a7 = 0.f;
    for (int base = s; base < e; base += 16) {
        int j = base + sub;
        int cl = 0;
        float vl = 0.0f;
        if (j < e) { uint2 t2 = csr[j]; cl = (int)t2.x; vl = __uint_as_float(t2.y); }
        int cnt = e - base; if (cnt > 16) cnt = 16;
        for (int k = 0; k < cnt; k += 4) {
            int l0 = quarter * 16 + k;
            int c0 = __shfl(cl, l0);
            int c1 = __shfl(cl, l0 + 1);
            int c2 = __shfl(cl, l0 + 2);
            int c3 = __shfl(cl, l0 + 3);
            float v0 = __shfl(vl, l0);
            float v1 = __shfl(vl, l0 + 1);
            float v2 = __shfl(vl, l0 + 2);
            float v3 = __shfl(vl, l0 + 3);  // entries past cnt have vl=0 -> contribute 0
            uint4 p0 = x4[(size_t)c0 * 16 + sub];
            uint4 p1 = x4[(size_t)c1 * 16 + sub];
            uint4 p2 = x4[(size_t)c2 * 16 + sub];
            uint4 p3 = x4[(size_t)c3 * 16 + sub];
            a0 += v0 * blo(p0.x); a1 += v0 * bhi(p0.x); a2 += v0 * blo(p0.y); a3 += v0 * bhi(p0.y);
            a4 += v0 * blo(p0.z); a5 += v0 * bhi(p0.z); a6 += v0 * blo(p0.w); a7 += v0 * bhi(p0.w);
            a0 += v1 * blo(p1.x); a1 += v1 * bhi(p1.x); a2 += v1 * blo(p1.y); a3 += v1 * bhi(p1.y);
            a4 += v1 * blo(p1.z); a5 += v1 * bhi(p1.z); a6 += v1 * blo(p1.w); a7 += v1 * bhi(p1.w);
            a0 += v2 * blo(p2.x); a1 += v2 * bhi(p2.x); a2 += v2 * blo(p2.y); a3 += v2 * bhi(p2.y);
            a4 += v2 * blo(p2.z); a5 += v2 * bhi(p2.z); a6 += v2 * blo(p2.w); a7 += v2 * bhi(p2.w);
            a0 += v3 * blo(p3.x); a1 += v3 * bhi(p3.x); a2 += v3 * blo(p3.y); a3 += v3 * bhi(p3.y);
            a4 += v3 * blo(p3.z); a5 += v3 * bhi(p3.z); a6 += v3 * blo(p3.w); a7 += v3 * bhi(p3.w);
        }
    }

    float id = 1.0f / deg[row];
    a0 *= id; a1 *= id; a2 *= id; a3 *= id; a4 *= id; a5 *= id; a6 *= id; a7 *= id;

    float ss = a0 * a0 + a1 * a1 + a2 * a2 + a3 * a3 + a4 * a4 + a5 * a5 + a6 * a6 + a7 * a7;
#pragma unroll
    for (int m = 1; m <= 8; m <<= 1) ss += __shfl_xor(ss, m);
    float nrm = fmaxf(sqrtf(ss), 1e-12f);

    x_next4[(size_t)row * 16 + sub] = make_uint4(pack2bf(a0, a1), pack2bf(a2, a3),
                                                 pack2bf(a4, a5), pack2bf(a6, a7));
    if (sub == 0) s_out[row] = weight / nrm;
}

// ---------------- hop 4: SpMM + combine acc(out) + per-block column stats ----------------
static __global__ __launch_bounds__(256) void spmm_last_kernel(
    const int* __restrict__ row_start, const uint2* __restrict__ csr,
    const uint4* __restrict__ xin, const float* __restrict__ deg,
    const uint4* __restrict__ x1, const uint4* __restrict__ x2, const uint4* __restrict__ x3,
    const float* __restrict__ s1, const float* __restrict__ s2, const float* __restrict__ s3,
    float* __restrict__ out, float* __restrict__ psum, float* __restrict__ psumsq, float weight) {
    __shared__ float shs[256 * 8];
    __shared__ float shq[256 * 8];
    int wave = threadIdx.x >> 6;
    int lane = threadIdx.x & 63;
    int quarter = lane >> 4;
    int sub = lane & 15;
    int row = blockIdx.x * 16 + wave * 4 + quarter;
    int s = row_start[row];
    int e = row_start[row + 1];

    float a0 = 0.f, a1 = 0.f, a2 = 0.f, a3 = 0.f, a4 = 0.f, a5 = 0.f, a6 = 0.f, a7 = 0.f;
    for (int base = s; base < e; base += 16) {
        int j = base + sub;
        int cl = 0;
        float vl = 0.0f;
        if (j < e) { uint2 t2 = csr[j]; cl = (int)t2.x; vl = __uint_as_float(t2.y); }
        int cnt = e - base; if (cnt > 16) cnt = 16;
        for (int k = 0; k < cnt; k += 4) {
            int l0 = quarter * 16 + k;
            int c0 = __shfl(cl, l0);
            int c1 = __shfl(cl, l0 + 1);
            int c2 = __shfl(cl, l0 + 2);
            int c3 = __shfl(cl, l0 + 3);
            float v0 = __shfl(vl, l0);
            float v1 = __shfl(vl, l0 + 1);
            float v2 = __shfl(vl, l0 + 2);
            float v3 = __shfl(vl, l0 + 3);
            uint4 p0 = xin[(size_t)c0 * 16 + sub];
            uint4 p1 = xin[(size_t)c1 * 16 + sub];
            uint4 p2 = xin[(size_t)c2 * 16 + sub];
            uint4 p3 = xin[(size_t)c3 * 16 + sub];
            a0 += v0 * blo(p0.x); a1 += v0 * bhi(p0.x); a2 += v0 * blo(p0.y); a3 += v0 * bhi(p0.y);
            a4 += v0 * blo(p0.z); a5 += v0 * bhi(p0.z); a6 += v0 * blo(p0.w); a7 += v0 * bhi(p0.w);
            a0 += v1 * blo(p1.x); a1 += v1 * bhi(p1.x); a2 += v1 * blo(p1.y); a3 += v1 * bhi(p1.y);
            a4 += v1 * blo(p1.z); a5 += v1 * bhi(p1.z); a6 += v1 * blo(p1.w); a7 += v1 * bhi(p1.w);
            a0 += v2 * blo(p2.x); a1 += v2 * bhi(p2.x); a2 += v2 * blo(p2.y); a3 += v2 * bhi(p2.y);
            a4 += v2 * blo(p2.z); a5 += v2 * bhi(p2.z); a6 += v2 * blo(p2.w); a7 += v2 * bhi(p2.w);
            a0 += v3 * blo(p3.x); a1 += v3 * bhi(p3.x); a2 += v3 * blo(p3.y); a3 += v3 * bhi(p3.y);
            a4 += v3 * blo(p3.z); a5 += v3 * bhi(p3.z); a6 += v3 * blo(p3.w); a7 += v3 * bhi(p3.w);
        }
    }

    float id = 1.0f / deg[row];
    a0 *= id; a1 *= id; a2 *= id; a3 *= id; a4 *= id; a5 *= id; a6 *= id; a7 *= id;

    float ss = a0 * a0 + a1 * a1 + a2 * a2 + a3 * a3 + a4 * a4 + a5 * a5 + a6 * a6 + a7 * a7;
#pragma unroll
    for (int m = 1; m <= 8; m <<= 1) ss += __shfl_xor(ss, m);
    float nrm = fmaxf(sqrtf(ss), 1e-12f);
    float w4 = weight / nrm;

    // combine: acc = s1*x1 + s2*x2 + s3*x3 + w4 * (f32 hop-4 row)
    size_t xi = (size_t)row * 16 + sub;
    float w1 = s1[row], w2 = s2[row], w3 = s3[row];
    uint4 q1 = x1[xi], q2 = x2[xi], q3 = x3[xi];
    float v[8];
    v[0] = w1 * blo(q1.x) + w2 * blo(q2.x) + w3 * blo(q3.x) + w4 * a0;
    v[1] = w1 * bhi(q1.x) + w2 * bhi(q2.x) + w3 * bhi(q3.x) + w4 * a1;
    v[2] = w1 * blo(q1.y) + w2 * blo(q2.y) + w3 * blo(q3.y) + w4 * a2;
    v[3] = w1 * bhi(q1.y) + w2 * bhi(q2.y) + w3 * bhi(q3.y) + w4 * a3;
    v[4] = w1 * blo(q1.z) + w2 * blo(q2.z) + w3 * blo(q3.z) + w4 * a4;
    v[5] = w1 * bhi(q1.z) + w2 * bhi(q2.z) + w3 * bhi(q3.z) + w4 * a5;
    v[6] = w1 * blo(q1.w) + w2 * blo(q2.w) + w3 * blo(q3.w) + w4 * a6;
    v[7] = w1 * bhi(q1.w) + w2 * bhi(q2.w) + w3 * bhi(q3.w) + w4 * a7;

    float4* out4 = (float4*)out;
    out4[(size_t)row * 32 + sub * 2]     = make_float4(v[0], v[1], v[2], v[3]);
    out4[(size_t)row * 32 + sub * 2 + 1] = make_float4(v[4], v[5], v[6], v[7]);

    int t = threadIdx.x;
#pragma unroll
    for (int j = 0; j < 8; ++j) {
        shs[t * 8 + j] = v[j];
        shq[t * 8 + j] = v[j] * v[j];
    }
    __syncthreads();
    if (t < DD) {  // column c = t; fold the 16 rows of this block
        int cs = t >> 3, cj = t & 7;
        float sacc = 0.0f, qacc = 0.0f;
        for (int g = 0; g < 16; ++g) {
            int src = (g * 16 + cs) * 8 + cj;
            sacc += shs[src];
            qacc += shq[src];
        }
        psum[(size_t)blockIdx.x * DD + t] = sacc;
        psumsq[(size_t)blockIdx.x * DD + t] = qacc;
    }
}

// ---------------- fold partials per column, compute mean/invstd ----------------
static __global__ __launch_bounds__(256) void fold_kernel(
    const float* __restrict__ psum, const float* __restrict__ psumsq,
    float* __restrict__ mean, float* __restrict__ invstd) {
    __shared__ double ss[256], qq[256];
    int c = blockIdx.x;   // 0..127
    int t = threadIdx.x;
    double s = 0.0, q = 0.0;
    for (int b = t; b < SPMM_NBLK; b += 256) {
        s += (double)psum[(size_t)b * DD + c];
        q += (double)psumsq[(size_t)b * DD + c];
    }
    ss[t] = s; qq[t] = q;
    __syncthreads();
    for (int off = 128; off > 0; off >>= 1) {
        if (t < off) { ss[t] += ss[t + off]; qq[t] += qq[t + off]; }
        __syncthreads();
    }
    if (t == 0) {
        double m = ss[0] / (double)NN;
        double var = (qq[0] - (double)NN * m * m) / (double)(NN - 1);
        if (var < 0.0) var = 0.0;
        double sd = sqrt(var);
        if (sd == 0.0) sd = 1.0;
        mean[c] = (float)m;
        invstd[c] = (float)(1.0 / sd);
    }
}

// ---------------- standardize in place (float4 vectorized) ----------------
static __global__ __launch_bounds__(256) void normalize_kernel(
    float* __restrict__ out, const float* __restrict__ mean, const float* __restrict__ invstd) {
    int i = blockIdx.x * blockDim.x + threadIdx.x;  // over NN*32 float4s
    int c4 = i & 31;
    float4 m = ((const float4*)mean)[c4];
    float4 is = ((const float4*)invstd)[c4];
    float4* out4 = (float4*)out;
    float4 v = out4[i];
    v.x = (v.x - m.x) * is.x;
    v.y = (v.y - m.y) * is.y;
    v.z = (v.z - m.z) * is.z;
    v.w = (v.w - m.w) * is.w;
    out4[i] = v;
}

extern "C" void kernel_launch(void* const* d_in, const int* in_sizes, int n_in,
                              void* d_out, int out_size, void* d_ws, size_t ws_size,
                              hipStream_t stream) {
    const int* erow = (const int*)d_in[0];
    const int* ecol = (const int*)d_in[1];
    const float* eval_ = (const float*)d_in[2];
    const float* R = (const float*)d_in[3];
    float* out = (float*)d_out;

    // workspace layout
    char* ws = (char*)d_ws;
    size_t off = 0;
    auto alloc = [&](size_t bytes) -> char* {
        char* p = ws + off;
        off += (bytes + 255) & ~(size_t)255;
        return p;
    };
    float* deg          = (float*)alloc(NN * sizeof(float));
    int* bucket_cursor  = (int*)alloc(NBKT * sizeof(int));
    int* row_start      = (int*)alloc((NN + 1) * sizeof(int));
    uint2* binned       = (uint2*)alloc((size_t)NBKT * BCAP * sizeof(uint2));
    uint2* csr          = (uint2*)alloc((size_t)NE * sizeof(uint2));
    uint4* x0           = (uint4*)alloc((size_t)NN * 16 * sizeof(uint4));  // bf16 packed
    uint4* x1           = (uint4*)alloc((size_t)NN * 16 * sizeof(uint4));
    uint4* x2           = (uint4*)alloc((size_t)NN * 16 * sizeof(uint4));
    uint4* x3           = (uint4*)alloc((size_t)NN * 16 * sizeof(uint4));
    float* s1           = (float*)alloc(NN * sizeof(float));
    float* s2           = (float*)alloc(NN * sizeof(float));
    float* s3           = (float*)alloc(NN * sizeof(float));
    float* psum         = (float*)alloc((size_t)SPMM_NBLK * DD * sizeof(float));
    float* psumsq       = (float*)alloc((size_t)SPMM_NBLK * DD * sizeof(float));
    float* meanbuf      = (float*)alloc(DD * sizeof(float));
    float* invstdb      = (float*)alloc(DD * sizeof(float));

    hipMemsetAsync(bucket_cursor, 0, NBKT * sizeof(int), stream);

    bin_kernel<<<NCHUNK, 512, 0, stream>>>(erow, ecol, eval_, bucket_cursor, binned);
    sort_kernel<<<NBKT, 512, 0, stream>>>(binned, bucket_cursor, csr, row_start, deg);
    x0_kernel<<<SPMM_NBLK, 256, 0, stream>>>(R, deg, x0);

    spmm_fused_kernel<<<SPMM_NBLK, 256, 0, stream>>>(row_start, csr, x0, deg, x1, s1, 1.0f);
    spmm_fused_kernel<<<SPMM_NBLK, 256, 0, stream>>>(row_start, csr, x1, deg, x2, s2, 1.0f);
    spmm_fused_kernel<<<SPMM_NBLK, 256, 0, stream>>>(row_start, csr, x2, deg, x3, s3, 7.81f);
    spmm_last_kernel<<<SPMM_NBLK, 256, 0, stream>>>(row_start, csr, x3, deg, x1, x2, x3,
                                                    s1, s2, s3, out, psum, psumsq, 45.28f);

    fold_kernel<<<DD, 256, 0, stream>>>(psum, psumsq, meanbuf, invstdb);
    normalize_kernel<<<NN * 32 / 256, 256, 0, stream>>>(out, meanbuf, invstdb);
}